// Round 8
// baseline (298.521 us; speedup 1.0000x reference)
//
#include <hip/hip_runtime.h>
#include <hip/hip_fp16.h>
#include <math.h>

#define DIV_UP(a,b) (((a)+(b)-1)/(b))

typedef _Float16 f16x8 __attribute__((ext_vector_type(8)));
typedef float    f32x4 __attribute__((ext_vector_type(4)));

// ======================= single-pass padded bin sort =======================
// SHIFT=9: bins of 512 targets; bin = col>>9 (K_used = ceil(N/512) <= 256).
// Entry packed as (src << 9) | (col & 511) — src<2^17, fits 26 bits.
#define SHIFT 9
#define TPB   (1 << SHIFT)          /* targets per bin = 512 */
#define LMASK (TPB - 1)
#define CHUNK 4096                  /* edges per binning block */

// --- init: per-bin cursors, CSR sentinel, and W1 -> f16 B-frag layout (16KB). ---
__global__ __launch_bounds__(256) void k_init(int* __restrict__ gcur, int cap,
                                              int* __restrict__ offsets,
                                              const float* __restrict__ W,
                                              _Float16* __restrict__ Wl, int N, int E) {
    const int t = threadIdx.x;
    gcur[t] = t * cap;
    if (t == 0) offsets[N] = E;
#pragma unroll
    for (int c = 0; c < 4; ++c) {
        int chunk = t + 256 * c;            // 0..1023
        int m0 = chunk & 15;
        int q  = (chunk >> 4) & 3;
        int ct = (chunk >> 6) & 1;
        int kc = chunk >> 7;
        int n  = ct * 16 + m0;
        f16x8 v;
#pragma unroll
        for (int j = 0; j < 8; ++j)
            v[j] = (_Float16)W[(kc * 32 + q * 8 + j) * 32 + n];
        *(f16x8*)&Wl[(size_t)chunk * 8] = v;   // 16B coalesced store
    }
}

// ================== k_bin: LDS-staged bin sort (standalone, attribution) ==================
__global__ __launch_bounds__(256) void k_bin(const int* __restrict__ row,
                                             const int* __restrict__ col,
                                             int* __restrict__ gcur,
                                             unsigned* __restrict__ binned,
                                             int E) {
    __shared__ int hist[256];
    __shared__ int loff[256];
    __shared__ int gbase[256];
    __shared__ int lcur[256];
    __shared__ unsigned staged[CHUNK];
    __shared__ unsigned char binOf[CHUNK];
    __shared__ int wtot[4];

    const int t = threadIdx.x;
    const int base = blockIdx.x * CHUNK;
    const int n = min(CHUNK, E - base);

    hist[t] = 0;
    __syncthreads();

    unsigned pk[CHUNK / 256];
    int bn[CHUNK / 256];
#pragma unroll
    for (int k = 0; k < CHUNK / 256; ++k) {
        int i = base + t + k * 256;
        if (i < E) {
            int c = col[i], r = row[i];
            bn[k] = c >> SHIFT;
            pk[k] = ((unsigned)r << SHIFT) | (unsigned)(c & LMASK);
            atomicAdd(&hist[bn[k]], 1);
        } else bn[k] = -1;
    }
    __syncthreads();

    // wave-level exclusive scan of hist[256] (4 waves x 64)
    const int hv = hist[t];
    int sc = hv;
#pragma unroll
    for (int s = 1; s < 64; s <<= 1) {
        int y = __shfl_up(sc, s, 64);
        if ((t & 63) >= s) sc += y;
    }
    if ((t & 63) == 63) wtot[t >> 6] = sc;
    __syncthreads();
    int woff = 0;
#pragma unroll
    for (int j = 0; j < 3; ++j) if (j < (t >> 6)) woff += wtot[j];
    const int excl = sc + woff - hv;
    gbase[t] = hv ? atomicAdd(&gcur[t], hv) : 0;   // reserve space in bin region
    lcur[t] = excl;
    loff[t] = excl;
    __syncthreads();

#pragma unroll
    for (int k = 0; k < CHUNK / 256; ++k) {
        if (bn[k] >= 0) {
            int p = atomicAdd(&lcur[bn[k]], 1);
            staged[p] = pk[k];
            binOf[p] = (unsigned char)bn[k];
        }
    }
    __syncthreads();

    for (int i = t; i < n; i += 256) {
        int bb = binOf[i];
        binned[gbase[bb] + (i - loff[bb])] = staged[i];
    }
}

// ================== k_gemm: h1[N][32] = x[N][256] @ W1 (MFMA f16) ==================
// SINGLE batch-pin asm: one asm consuming all 16 fragment .x components forces all
// 16 dwordx4 loads to be issued+completed before one program point (separate per-
// fragment asms allowed load-pin-load-pin serialization — round-7, VGPR 52).
__global__ __launch_bounds__(256) void k_gemm(const float* __restrict__ x,
                                              const _Float16* __restrict__ Wl,
                                              __half* __restrict__ h1, int N) {
    __shared__ __align__(16) _Float16 WlT[8192];   // 16KB
    const int t = threadIdx.x;
    const int gb = blockIdx.x;

    const uint4* Wg4 = (const uint4*)Wl;
#pragma unroll
    for (int i = 0; i < 4; ++i)
        ((uint4*)WlT)[t + 256 * i] = Wg4[t + 256 * i];
    __syncthreads();

    const int lane = t & 63;
    const int wv   = t >> 6;        // wave 0..3
    const int m    = lane & 15;
    const int q    = lane >> 4;     // 0..3

    const int rowA   = gb * 64 + wv * 16 + m;
    const int rclamp = min(rowA, N - 1);
    const float* xr  = x + (long long)rclamp * 256 + q * 8;

    float4 va[16];
#pragma unroll
    for (int kc = 0; kc < 8; ++kc) {
        va[2 * kc]     = *(const float4*)(xr + kc * 32);
        va[2 * kc + 1] = *(const float4*)(xr + kc * 32 + 4);
    }
    asm volatile("" ::
        "v"(va[0].x),  "v"(va[1].x),  "v"(va[2].x),  "v"(va[3].x),
        "v"(va[4].x),  "v"(va[5].x),  "v"(va[6].x),  "v"(va[7].x),
        "v"(va[8].x),  "v"(va[9].x),  "v"(va[10].x), "v"(va[11].x),
        "v"(va[12].x), "v"(va[13].x), "v"(va[14].x), "v"(va[15].x));
    __builtin_amdgcn_sched_barrier(0);

    f32x4 c0 = {0.f, 0.f, 0.f, 0.f}, c1 = {0.f, 0.f, 0.f, 0.f};
#pragma unroll
    for (int kc = 0; kc < 8; ++kc) {
        f16x8 b0 = *(const f16x8*)&WlT[(size_t)((kc * 2 + 0) * 64 + lane) * 8];
        f16x8 b1 = *(const f16x8*)&WlT[(size_t)((kc * 2 + 1) * 64 + lane) * 8];
        float4 v0 = va[2 * kc], v1 = va[2 * kc + 1];
        f16x8 a;
        a[0] = (_Float16)v0.x; a[1] = (_Float16)v0.y;
        a[2] = (_Float16)v0.z; a[3] = (_Float16)v0.w;
        a[4] = (_Float16)v1.x; a[5] = (_Float16)v1.y;
        a[6] = (_Float16)v1.z; a[7] = (_Float16)v1.w;
        c0 = __builtin_amdgcn_mfma_f32_16x16x32_f16(a, b0, c0, 0, 0, 0);
        c1 = __builtin_amdgcn_mfma_f32_16x16x32_f16(a, b1, c1, 0, 0, 0);
    }

    const int orow = gb * 64 + wv * 16 + q * 4;
#pragma unroll
    for (int r = 0; r < 4; ++r) {
        int gr = orow + r;
        if (gr < N) {
            h1[gr * 32 + m]      = __float2half(c0[r]);
            h1[gr * 32 + 16 + m] = __float2half(c1[r]);
        }
    }
}

// --- CSR build only (no h1 prescale — dinv applied at gather in agg1).
//     1024 threads/block, shuffle-based scans, two passes over the bin region. ---
__global__ __launch_bounds__(1024) void k_csr2(const unsigned* __restrict__ binned,
                                               const int* __restrict__ gcur, int cap,
                                               int* __restrict__ offsets,
                                               float* __restrict__ dinv,
                                               int* __restrict__ srcs, int N) {
    __shared__ int h[TPB];
    __shared__ int cur[TPB];
    __shared__ int wred[16];
    const int t = threadIdx.x, b = blockIdx.x;
    const int lane = t & 63, wv = t >> 6;      // 16 waves
    const int beg = b * cap, end = gcur[b];

    // obase = sum_{i<b} (gcur[i]-i*cap) via wave butterfly (contributions only t<256)
    int contrib = (t < 256 && t < b) ? (gcur[t] - t * cap) : 0;
#pragma unroll
    for (int s = 1; s < 64; s <<= 1) contrib += __shfl_xor(contrib, s, 64);
    if (t < TPB) h[t] = 0;
    if (lane == 0 && wv < 4) wred[wv] = contrib;
    __syncthreads();
    const int obase = wred[0] + wred[1] + wred[2] + wred[3];

    for (int i = beg + t; i < end; i += 1024)
        atomicAdd(&h[binned[i] & LMASK], 1);
    __syncthreads();

    // exclusive scan of h[512] via 8 wave-scans + cross-wave fixup
    const int cnt = (t < TPB) ? h[t] : 0;
    int sc = cnt;
#pragma unroll
    for (int s = 1; s < 64; s <<= 1) {
        int y = __shfl_up(sc, s, 64);
        if (lane >= s) sc += y;
    }
    if (t < TPB && lane == 63) wred[8 + wv] = sc;   // wv 0..7
    __syncthreads();
    if (t < TPB) {
        int woff = 0;
        for (int j = 0; j < wv; ++j) woff += wred[8 + j];
        const int excl = sc + woff - cnt;
        const int g = (b << SHIFT) + t;
        const int pos0 = obase + excl;
        if (g < N) {
            offsets[g] = pos0;
            dinv[g] = rsqrtf((float)(1 + cnt));   // +1 self-loop
        }
        cur[t] = pos0;
    }
    __syncthreads();

    for (int i = beg + t; i < end; i += 1024) {
        unsigned v = binned[i];
        int pos = atomicAdd(&cur[v & LMASK], 1);
        srcs[pos] = (int)(v >> SHIFT);
    }
}

// ====== agg1: Σ dinv[src]*h1[src]; fuse relu+b1+W2 GEMV; write tw = dinv*t ======
// half-wave per node; lane = (sub=edge-slot 0..7, q=feature-octet 0..3).
// dinv gathered per edge (400KB L2-resident) and folded into the tail mask.
__global__ void k_agg1(const int* __restrict__ offsets, const int* __restrict__ srcs,
                       const float* __restrict__ dinv, const __half* __restrict__ h1,
                       const float* __restrict__ b1, const float* __restrict__ W2,
                       __half2* __restrict__ tw, int N) {
    long long g = (long long)blockIdx.x * blockDim.x + threadIdx.x;
    int node = (int)(g >> 5), f = (int)(g & 31);
    if (node >= N) return;
    const int sub = f >> 2, q = f & 3;
    const int beg = offsets[node], end = offsets[node + 1];
    const uint4* h4 = (const uint4*)h1;   // 4 uint4 per 32-feat row

    float a0 = 0.f, a1 = 0.f, a2 = 0.f, a3 = 0.f;
    float a4 = 0.f, a5 = 0.f, a6 = 0.f, a7 = 0.f;

    for (int j = beg; j < end; j += 16) {
        int e0 = j + sub, e1 = j + 8 + sub;
        int s0 = srcs[min(e0, end - 1)];
        int s1 = srcs[min(e1, end - 1)];
        float dm0 = dinv[s0] * ((e0 < end) ? 1.f : 0.f);
        float dm1 = dinv[s1] * ((e1 < end) ? 1.f : 0.f);
        uint4 rv0 = h4[s0 * 4 + q];
        uint4 rv1 = h4[s1 * 4 + q];
        __half2 p; float2 u;
        p = *(__half2*)&rv0.x; u = __half22float2(p); a0 = fmaf(u.x, dm0, a0); a1 = fmaf(u.y, dm0, a1);
        p = *(__half2*)&rv0.y; u = __half22float2(p); a2 = fmaf(u.x, dm0, a2); a3 = fmaf(u.y, dm0, a3);
        p = *(__half2*)&rv0.z; u = __half22float2(p); a4 = fmaf(u.x, dm0, a4); a5 = fmaf(u.y, dm0, a5);
        p = *(__half2*)&rv0.w; u = __half22float2(p); a6 = fmaf(u.x, dm0, a6); a7 = fmaf(u.y, dm0, a7);
        p = *(__half2*)&rv1.x; u = __half22float2(p); a0 = fmaf(u.x, dm1, a0); a1 = fmaf(u.y, dm1, a1);
        p = *(__half2*)&rv1.y; u = __half22float2(p); a2 = fmaf(u.x, dm1, a2); a3 = fmaf(u.y, dm1, a3);
        p = *(__half2*)&rv1.z; u = __half22float2(p); a4 = fmaf(u.x, dm1, a4); a5 = fmaf(u.y, dm1, a5);
        p = *(__half2*)&rv1.w; u = __half22float2(p); a6 = fmaf(u.x, dm1, a6); a7 = fmaf(u.y, dm1, a7);
    }
#pragma unroll
    for (int s = 4; s < 32; s <<= 1) {
        a0 += __shfl_xor(a0, s, 32); a1 += __shfl_xor(a1, s, 32);
        a2 += __shfl_xor(a2, s, 32); a3 += __shfl_xor(a3, s, 32);
        a4 += __shfl_xor(a4, s, 32); a5 += __shfl_xor(a5, s, 32);
        a6 += __shfl_xor(a6, s, 32); a7 += __shfl_xor(a7, s, 32);
    }
    if (sub == 0) {   // lanes 0..3 hold full sums for feature octets q=0..3
        float di = dinv[node];
        uint4 rv = h4[node * 4 + q];   // self-loop row (raw h1)
        float sf[8];
        {
            __half2 p; float2 u;
            p = *(__half2*)&rv.x; u = __half22float2(p); sf[0] = u.x; sf[1] = u.y;
            p = *(__half2*)&rv.y; u = __half22float2(p); sf[2] = u.x; sf[3] = u.y;
            p = *(__half2*)&rv.z; u = __half22float2(p); sf[4] = u.x; sf[5] = u.y;
            p = *(__half2*)&rv.w; u = __half22float2(p); sf[6] = u.x; sf[7] = u.y;
        }
        float av[8] = {a0, a1, a2, a3, a4, a5, a6, a7};
        float t0 = 0.f, t1 = 0.f;
#pragma unroll
        for (int k = 0; k < 8; ++k) {
            int feat = q * 8 + k;
            float hv = fmaf(di, av[k] + di * sf[k], b1[feat]);
            hv = fmaxf(hv, 0.f);
            t0 = fmaf(hv, W2[feat * 2 + 0], t0);
            t1 = fmaf(hv, W2[feat * 2 + 1], t1);
        }
        t0 += __shfl_xor(t0, 1, 32); t0 += __shfl_xor(t0, 2, 32);
        t1 += __shfl_xor(t1, 1, 32); t1 += __shfl_xor(t1, 2, 32);
        if (q == 0) tw[node] = __floats2half2_rn(di * t0, di * t1);
    }
}

// ====== agg2: Σ tw[src] (half2, 4B/edge); 16 lanes/node; fuse b2 + log_softmax ======
__global__ void k_agg2(const int* __restrict__ offsets, const int* __restrict__ srcs,
                       const float* __restrict__ dinv, const __half2* __restrict__ tw,
                       const float* __restrict__ b2, float* __restrict__ out, int N) {
    long long g = (long long)blockIdx.x * blockDim.x + threadIdx.x;
    int node = (int)(g >> 4), f = (int)(g & 15);
    if (node >= N) return;
    int beg = offsets[node], end = offsets[node + 1];
    float a0 = 0.f, a1 = 0.f;
    for (int j = beg + f; j < end; j += 16) {
        int s = srcs[j];
        float2 u = __half22float2(tw[s]);
        a0 += u.x;
        a1 += u.y;
    }
#pragma unroll
    for (int s = 8; s; s >>= 1) {   // masks <16 stay within the 16-lane group
        a0 += __shfl_xor(a0, s, 64);
        a1 += __shfl_xor(a1, s, 64);
    }
    if (f == 0) {
        float di = dinv[node];
        float2 u = __half22float2(tw[node]);
        float z0 = di * (a0 + u.x) + b2[0];
        float z1 = di * (a1 + u.y) + b2[1];
        float m = fmaxf(z0, z1);
        float lse = m + logf(expf(z0 - m) + expf(z1 - m));
        ((float2*)out)[node] = float2{z0 - lse, z1 - lse};
    }
}

extern "C" void kernel_launch(void* const* d_in, const int* in_sizes, int n_in,
                              void* d_out, int out_size, void* d_ws, size_t ws_size,
                              hipStream_t stream) {
    const float* x  = (const float*)d_in[0];
    const int*   ei = (const int*)d_in[1];
    const float* W1 = (const float*)d_in[2];
    const float* b1 = (const float*)d_in[3];
    const float* W2 = (const float*)d_in[4];
    const float* b2 = (const float*)d_in[5];

    const int H = in_sizes[3];           // 32
    const int D = in_sizes[2] / H;       // 256
    const int N = in_sizes[0] / D;       // 100000
    const int E = in_sizes[1] / 2;       // 3200000
    (void)H; (void)n_in; (void)out_size; (void)ws_size;

    const int* row = ei;                 // sources
    const int* col = ei + E;             // targets

    const int K_used = ((N - 1) >> SHIFT) + 1;        // 196 bins
    const int cap    = (DIV_UP(E, K_used) * 5 / 4 + 255) & ~255;  // +25% margin
    const int nchunk = DIV_UP(E, CHUNK);              // 782 binning blocks
    const int gemmB  = DIV_UP(N, 64);                 // 1563 gemm blocks

    char* p = (char*)d_ws;
    auto alloc = [&](size_t bytes) { char* q = p; p += (bytes + 255) & ~(size_t)255; return q; };
    int*      offsets = (int*)     alloc((size_t)(N + 1) * 4);
    int*      gcur    = (int*)     alloc(256 * 4);
    _Float16* Wl      = (_Float16*)alloc(8192 * 2);
    float*    dinv    = (float*)   alloc((size_t)N * 4);
    unsigned* binned  = (unsigned*)alloc((size_t)K_used * cap * 4);
    __half*   h1      = (__half*)  alloc((size_t)N * 32 * 2);
    int*      srcs    = (int*)     alloc((size_t)E * 4);
    __half2*  tw      = (__half2*) alloc((size_t)N * 4);

    k_init <<<1, 256, 0, stream>>>(gcur, cap, offsets, W1, Wl, N, E);
    k_bin  <<<nchunk, 256, 0, stream>>>(row, col, gcur, binned, E);
    k_gemm <<<gemmB, 256, 0, stream>>>(x, Wl, h1, N);
    k_csr2 <<<K_used, 1024, 0, stream>>>(binned, gcur, cap, offsets, dinv, srcs, N);
    k_agg1 <<<(int)DIV_UP((long long)N * 32, 256), 256, 0, stream>>>(offsets, srcs, dinv, h1, b1, W2, tw, N);
    k_agg2 <<<(int)DIV_UP((long long)N * 16, 256), 256, 0, stream>>>(offsets, srcs, dinv, tw, b2, (float*)d_out, N);
}

// Round 9
// 280.427 us; speedup vs baseline: 1.0645x; 1.0645x over previous
//
#include <hip/hip_runtime.h>
#include <hip/hip_fp16.h>
#include <math.h>

#define DIV_UP(a,b) (((a)+(b)-1)/(b))

typedef _Float16 f16x8 __attribute__((ext_vector_type(8)));
typedef float    f32x4 __attribute__((ext_vector_type(4)));

// ======================= single-pass padded bin sort =======================
// SHIFT=9: bins of 512 targets; bin = col>>9 (K_used = ceil(N/512) <= 256).
// Entry packed as (src << 9) | (col & 511) — src<2^17, fits 26 bits.
#define SHIFT 9
#define TPB   (1 << SHIFT)          /* targets per bin = 512 */
#define LMASK (TPB - 1)
#define CHUNK 4096                  /* edges per binning block */

// --- init: per-bin cursors, CSR sentinel, and W1 -> f16 B-frag layout (16KB). ---
__global__ __launch_bounds__(256) void k_init(int* __restrict__ gcur, int cap,
                                              int* __restrict__ offsets,
                                              const float* __restrict__ W,
                                              _Float16* __restrict__ Wl, int N, int E) {
    const int t = threadIdx.x;
    gcur[t] = t * cap;
    if (t == 0) offsets[N] = E;
#pragma unroll
    for (int c = 0; c < 4; ++c) {
        int chunk = t + 256 * c;            // 0..1023
        int m0 = chunk & 15;
        int q  = (chunk >> 4) & 3;
        int ct = (chunk >> 6) & 1;
        int kc = chunk >> 7;
        int n  = ct * 16 + m0;
        f16x8 v;
#pragma unroll
        for (int j = 0; j < 8; ++j)
            v[j] = (_Float16)W[(kc * 32 + q * 8 + j) * 32 + n];
        *(f16x8*)&Wl[(size_t)chunk * 8] = v;   // 16B coalesced store
    }
}

// ================== FAT kernel: gemm1 + binA, interleaved block roles ==================
// (round-5 verbatim — verified 62us/274.5 total)
__global__ __launch_bounds__(256) void k_fat(const float* __restrict__ x,
                                             const _Float16* __restrict__ Wl,
                                             __half* __restrict__ h1,
                                             const int* __restrict__ row,
                                             const int* __restrict__ col,
                                             int* __restrict__ gcur,
                                             unsigned* __restrict__ binned,
                                             int E, int N, int nchunk) {
    __shared__ __align__(16) char smem[24608];   // union: gemm WlT 16KB | binA 24KB + wtot
    const int t = threadIdx.x;
    const int bid = blockIdx.x;
    const bool isBin = (bid < 2 * nchunk) && (bid & 1);

    if (!isBin) {
        // ------------------- GEMM branch -------------------
        const int gb = (bid < 2 * nchunk) ? (bid >> 1) : (bid - nchunk);
        _Float16* WlT = (_Float16*)smem;

        const uint4* Wg4 = (const uint4*)Wl;
#pragma unroll
        for (int i = 0; i < 4; ++i)
            ((uint4*)WlT)[t + 256 * i] = Wg4[t + 256 * i];
        __syncthreads();

        const int lane = t & 63;
        const int wv   = t >> 6;        // wave 0..3
        const int m    = lane & 15;
        const int q    = lane >> 4;     // 0..3

        const int rowA   = gb * 64 + wv * 16 + m;
        const int rclamp = min(rowA, N - 1);
        const float* xr  = x + (long long)rclamp * 256 + q * 8;

        float4 va[16];
#pragma unroll
        for (int kc = 0; kc < 8; ++kc) {
            va[2 * kc]     = *(const float4*)(xr + kc * 32);
            va[2 * kc + 1] = *(const float4*)(xr + kc * 32 + 4);
        }
        __builtin_amdgcn_sched_barrier(0);

        f32x4 c0 = {0.f, 0.f, 0.f, 0.f}, c1 = {0.f, 0.f, 0.f, 0.f};
#pragma unroll
        for (int kc = 0; kc < 8; ++kc) {
            f16x8 b0 = *(const f16x8*)&WlT[(size_t)((kc * 2 + 0) * 64 + lane) * 8];
            f16x8 b1 = *(const f16x8*)&WlT[(size_t)((kc * 2 + 1) * 64 + lane) * 8];
            float4 v0 = va[2 * kc], v1 = va[2 * kc + 1];
            f16x8 a;
            a[0] = (_Float16)v0.x; a[1] = (_Float16)v0.y;
            a[2] = (_Float16)v0.z; a[3] = (_Float16)v0.w;
            a[4] = (_Float16)v1.x; a[5] = (_Float16)v1.y;
            a[6] = (_Float16)v1.z; a[7] = (_Float16)v1.w;
            c0 = __builtin_amdgcn_mfma_f32_16x16x32_f16(a, b0, c0, 0, 0, 0);
            c1 = __builtin_amdgcn_mfma_f32_16x16x32_f16(a, b1, c1, 0, 0, 0);
        }

        const int orow = gb * 64 + wv * 16 + q * 4;
#pragma unroll
        for (int r = 0; r < 4; ++r) {
            int gr = orow + r;
            if (gr < N) {
                h1[gr * 32 + m]      = __float2half(c0[r]);
                h1[gr * 32 + 16 + m] = __float2half(c1[r]);
            }
        }
    } else {
        // ------------------- binA branch -------------------
        int* hist  = (int*)smem;
        int* loff  = hist + 256;
        int* gbase = loff + 256;
        int* lcur  = gbase + 256;
        unsigned* staged     = (unsigned*)(smem + 4096);
        unsigned char* binOf = (unsigned char*)(smem + 4096 + 16384);
        int* wtot            = (int*)(smem + 4096 + 16384 + 4096);

        const int base = (bid >> 1) * CHUNK;
        const int n = min(CHUNK, E - base);

        hist[t] = 0;
        __syncthreads();

        unsigned pk[CHUNK / 256];
        int bn[CHUNK / 256];
#pragma unroll
        for (int k = 0; k < CHUNK / 256; ++k) {
            int i = base + t + k * 256;
            if (i < E) {
                int c = col[i], r = row[i];
                bn[k] = c >> SHIFT;
                pk[k] = ((unsigned)r << SHIFT) | (unsigned)(c & LMASK);
                atomicAdd(&hist[bn[k]], 1);
            } else bn[k] = -1;
        }
        __syncthreads();

        const int hv = hist[t];
        int sc = hv;
#pragma unroll
        for (int s = 1; s < 64; s <<= 1) {
            int y = __shfl_up(sc, s, 64);
            if ((t & 63) >= s) sc += y;
        }
        if ((t & 63) == 63) wtot[t >> 6] = sc;
        __syncthreads();
        int woff = 0;
#pragma unroll
        for (int j = 0; j < 3; ++j) if (j < (t >> 6)) woff += wtot[j];
        const int excl = sc + woff - hv;
        gbase[t] = hv ? atomicAdd(&gcur[t], hv) : 0;   // reserve space in bin region
        lcur[t] = excl;
        loff[t] = excl;
        __syncthreads();

#pragma unroll
        for (int k = 0; k < CHUNK / 256; ++k) {
            if (bn[k] >= 0) {
                int p = atomicAdd(&lcur[bn[k]], 1);
                staged[p] = pk[k];
                binOf[p] = (unsigned char)bn[k];
            }
        }
        __syncthreads();

        for (int i = t; i < n; i += 256) {
            int bb = binOf[i];
            binned[gbase[bb] + (i - loff[bb])] = staged[i];
        }
    }
}

// --- CSR build + h1 prescale, 2 blocks per bin (half-bin each), 512 threads.
//     Each half-block reads the full bin region but histograms/scatters only its
//     256 locs (the other half is a register count for the upper half's base).
//     Halves per-block LDS-atomic + scatter serial work; 392 blocks, ~3KB LDS.
__global__ __launch_bounds__(512) void k_csr2(const unsigned* __restrict__ binned,
                                              const int* __restrict__ gcur, int cap,
                                              int* __restrict__ offsets,
                                              float* __restrict__ dinv,
                                              int* __restrict__ srcs,
                                              __half* __restrict__ h1, int N) {
    __shared__ int h[256];
    __shared__ int cur[256];
    __shared__ float sdi[256];
    __shared__ int wred[12];
    const int t = threadIdx.x, bb = blockIdx.x;
    const int b = bb >> 1, half = bb & 1;
    const int lane = t & 63, wv = t >> 6;       // 8 waves
    const int beg = b * cap, end = gcur[b];

    // obase = sum_{i<b} (gcur[i]-i*cap) via wave butterfly (contributions only t<256)
    int contrib = (t < 256 && t < b) ? (gcur[t] - t * cap) : 0;
#pragma unroll
    for (int s = 1; s < 64; s <<= 1) contrib += __shfl_xor(contrib, s, 64);
    if (t < 256) h[t] = 0;
    if (lane == 0 && wv < 4) wred[wv] = contrib;
    __syncthreads();
    const int obase = wred[0] + wred[1] + wred[2] + wred[3];

    // pass 1: histogram MY half's locs; count other-half edges in a register
    int other = 0;
    for (int i = beg + t; i < end; i += 512) {
        unsigned v = binned[i];
        int loc = v & LMASK;
        if ((loc >> 8) == half) atomicAdd(&h[loc & 255], 1);
        else ++other;
    }
#pragma unroll
    for (int s = 1; s < 64; s <<= 1) other += __shfl_xor(other, s, 64);
    if (lane == 0) wred[4 + wv] = other;        // wred[4..11]
    __syncthreads();

    // exclusive scan of h[256] (threads 0..255, waves 0..3)
    const int cnt = (t < 256) ? h[t] : 0;
    int sc = cnt;
#pragma unroll
    for (int s = 1; s < 64; s <<= 1) {
        int y = __shfl_up(sc, s, 64);
        if (lane >= s) sc += y;
    }
    if (t < 256 && lane == 63) wred[wv] = sc;   // reuse wred[0..3] (obase in register)
    __syncthreads();

    int base2 = 0;                               // upper half starts after all lower edges
    if (half) {
#pragma unroll
        for (int j = 0; j < 8; ++j) base2 += wred[4 + j];
    }
    if (t < 256) {
        int woff = 0;
        for (int j = 0; j < wv; ++j) woff += wred[j];
        const int excl = sc + woff - cnt;
        const int pos0 = obase + base2 + excl;
        const int g = (b << SHIFT) + (half << 8) + t;
        float di = 0.f;
        if (g < N) {
            offsets[g] = pos0;
            di = rsqrtf((float)(1 + cnt));       // +1 self-loop
            dinv[g] = di;
        }
        cur[t] = pos0;
        sdi[t] = di;
    }
    __syncthreads();

    // pass 2: scatter MY half's edges
    for (int i = beg + t; i < end; i += 512) {
        unsigned v = binned[i];
        int loc = v & LMASK;
        if ((loc >> 8) == half) {
            int pos = atomicAdd(&cur[loc & 255], 1);
            srcs[pos] = (int)(v >> SHIFT);
        }
    }

    // prescale my half's h1 rows: h1w = dinv*h1 (32B per thread, 2 threads/row)
    const int node = (b << SHIFT) + (half << 8) + (t >> 1);
    if (node < N) {
        float di = sdi[t >> 1];
        uint4* hp4 = (uint4*)(h1 + (size_t)node * 32) + (t & 1) * 2;
#pragma unroll
        for (int k4 = 0; k4 < 2; ++k4) {
            uint4 v = hp4[k4];
            __half2* ph = (__half2*)&v;
#pragma unroll
            for (int k2 = 0; k2 < 4; ++k2) {
                float2 u = __half22float2(ph[k2]);
                ph[k2] = __floats2half2_rn(u.x * di, u.y * di);
            }
            hp4[k4] = v;
        }
    }
}

// ====== agg1: Σ h1w[src]; fuse relu+b1+W2 GEMV; write tw = dinv*t (half2) ======
// (round-5 verbatim)
__global__ void k_agg1(const int* __restrict__ offsets, const int* __restrict__ srcs,
                       const float* __restrict__ dinv, const __half* __restrict__ h1w,
                       const float* __restrict__ b1, const float* __restrict__ W2,
                       __half2* __restrict__ tw, int N) {
    long long g = (long long)blockIdx.x * blockDim.x + threadIdx.x;
    int node = (int)(g >> 5), f = (int)(g & 31);
    if (node >= N) return;
    const int sub = f >> 2, q = f & 3;
    const int beg = offsets[node], end = offsets[node + 1];
    const uint4* h4 = (const uint4*)h1w;   // 4 uint4 per 32-feat row

    float a0 = 0.f, a1 = 0.f, a2 = 0.f, a3 = 0.f;
    float a4 = 0.f, a5 = 0.f, a6 = 0.f, a7 = 0.f;

    for (int j = beg; j < end; j += 16) {
        int e0 = j + sub, e1 = j + 8 + sub;
        int s0 = srcs[min(e0, end - 1)];
        int s1 = srcs[min(e1, end - 1)];
        float m0 = (e0 < end) ? 1.f : 0.f;
        float m1 = (e1 < end) ? 1.f : 0.f;
        uint4 rv0 = h4[s0 * 4 + q];
        uint4 rv1 = h4[s1 * 4 + q];
        __half2 p; float2 u;
        p = *(__half2*)&rv0.x; u = __half22float2(p); a0 = fmaf(u.x, m0, a0); a1 = fmaf(u.y, m0, a1);
        p = *(__half2*)&rv0.y; u = __half22float2(p); a2 = fmaf(u.x, m0, a2); a3 = fmaf(u.y, m0, a3);
        p = *(__half2*)&rv0.z; u = __half22float2(p); a4 = fmaf(u.x, m0, a4); a5 = fmaf(u.y, m0, a5);
        p = *(__half2*)&rv0.w; u = __half22float2(p); a6 = fmaf(u.x, m0, a6); a7 = fmaf(u.y, m0, a7);
        p = *(__half2*)&rv1.x; u = __half22float2(p); a0 = fmaf(u.x, m1, a0); a1 = fmaf(u.y, m1, a1);
        p = *(__half2*)&rv1.y; u = __half22float2(p); a2 = fmaf(u.x, m1, a2); a3 = fmaf(u.y, m1, a3);
        p = *(__half2*)&rv1.z; u = __half22float2(p); a4 = fmaf(u.x, m1, a4); a5 = fmaf(u.y, m1, a5);
        p = *(__half2*)&rv1.w; u = __half22float2(p); a6 = fmaf(u.x, m1, a6); a7 = fmaf(u.y, m1, a7);
    }
#pragma unroll
    for (int s = 4; s < 32; s <<= 1) {
        a0 += __shfl_xor(a0, s, 32); a1 += __shfl_xor(a1, s, 32);
        a2 += __shfl_xor(a2, s, 32); a3 += __shfl_xor(a3, s, 32);
        a4 += __shfl_xor(a4, s, 32); a5 += __shfl_xor(a5, s, 32);
        a6 += __shfl_xor(a6, s, 32); a7 += __shfl_xor(a7, s, 32);
    }
    if (sub == 0) {   // lanes 0..3 hold full sums for feature octets q=0..3
        float di = dinv[node];
        uint4 rv = h4[node * 4 + q];   // self-loop row (already dinv-scaled)
        float sf[8];
        {
            __half2 p; float2 u;
            p = *(__half2*)&rv.x; u = __half22float2(p); sf[0] = u.x; sf[1] = u.y;
            p = *(__half2*)&rv.y; u = __half22float2(p); sf[2] = u.x; sf[3] = u.y;
            p = *(__half2*)&rv.z; u = __half22float2(p); sf[4] = u.x; sf[5] = u.y;
            p = *(__half2*)&rv.w; u = __half22float2(p); sf[6] = u.x; sf[7] = u.y;
        }
        float av[8] = {a0, a1, a2, a3, a4, a5, a6, a7};
        float t0 = 0.f, t1 = 0.f;
#pragma unroll
        for (int k = 0; k < 8; ++k) {
            int feat = q * 8 + k;
            float hv = fmaf(di, av[k] + sf[k], b1[feat]);
            hv = fmaxf(hv, 0.f);
            t0 = fmaf(hv, W2[feat * 2 + 0], t0);
            t1 = fmaf(hv, W2[feat * 2 + 1], t1);
        }
        t0 += __shfl_xor(t0, 1, 32); t0 += __shfl_xor(t0, 2, 32);
        t1 += __shfl_xor(t1, 1, 32); t1 += __shfl_xor(t1, 2, 32);
        if (q == 0) tw[node] = __floats2half2_rn(di * t0, di * t1);
    }
}

// ====== agg2: Σ tw[src] (half2, 4B/edge); 16 lanes/node; fuse b2 + log_softmax ======
__global__ void k_agg2(const int* __restrict__ offsets, const int* __restrict__ srcs,
                       const float* __restrict__ dinv, const __half2* __restrict__ tw,
                       const float* __restrict__ b2, float* __restrict__ out, int N) {
    long long g = (long long)blockIdx.x * blockDim.x + threadIdx.x;
    int node = (int)(g >> 4), f = (int)(g & 15);
    if (node >= N) return;
    int beg = offsets[node], end = offsets[node + 1];
    float a0 = 0.f, a1 = 0.f;
    for (int j = beg + f; j < end; j += 16) {
        int s = srcs[j];
        float2 u = __half22float2(tw[s]);
        a0 += u.x;
        a1 += u.y;
    }
#pragma unroll
    for (int s = 8; s; s >>= 1) {   // masks <16 stay within the 16-lane group
        a0 += __shfl_xor(a0, s, 64);
        a1 += __shfl_xor(a1, s, 64);
    }
    if (f == 0) {
        float di = dinv[node];
        float2 u = __half22float2(tw[node]);
        float z0 = di * (a0 + u.x) + b2[0];
        float z1 = di * (a1 + u.y) + b2[1];
        float m = fmaxf(z0, z1);
        float lse = m + logf(expf(z0 - m) + expf(z1 - m));
        ((float2*)out)[node] = float2{z0 - lse, z1 - lse};
    }
}

extern "C" void kernel_launch(void* const* d_in, const int* in_sizes, int n_in,
                              void* d_out, int out_size, void* d_ws, size_t ws_size,
                              hipStream_t stream) {
    const float* x  = (const float*)d_in[0];
    const int*   ei = (const int*)d_in[1];
    const float* W1 = (const float*)d_in[2];
    const float* b1 = (const float*)d_in[3];
    const float* W2 = (const float*)d_in[4];
    const float* b2 = (const float*)d_in[5];

    const int H = in_sizes[3];           // 32
    const int D = in_sizes[2] / H;       // 256
    const int N = in_sizes[0] / D;       // 100000
    const int E = in_sizes[1] / 2;       // 3200000
    (void)H; (void)n_in; (void)out_size; (void)ws_size;

    const int* row = ei;                 // sources
    const int* col = ei + E;             // targets

    const int K_used = ((N - 1) >> SHIFT) + 1;        // 196 bins
    const int cap    = (DIV_UP(E, K_used) * 5 / 4 + 255) & ~255;  // +25% margin
    const int nchunk = DIV_UP(E, CHUNK);              // 782 binning blocks
    const int gemmB  = DIV_UP(N, 64);                 // 1563 gemm blocks

    char* p = (char*)d_ws;
    auto alloc = [&](size_t bytes) { char* q = p; p += (bytes + 255) & ~(size_t)255; return q; };
    int*      offsets = (int*)     alloc((size_t)(N + 1) * 4);
    int*      gcur    = (int*)     alloc(256 * 4);
    _Float16* Wl      = (_Float16*)alloc(8192 * 2);
    float*    dinv    = (float*)   alloc((size_t)N * 4);
    unsigned* binned  = (unsigned*)alloc((size_t)K_used * cap * 4);
    __half*   h1      = (__half*)  alloc((size_t)N * 32 * 2);
    int*      srcs    = (int*)     alloc((size_t)E * 4);
    __half2*  tw      = (__half2*) alloc((size_t)N * 4);

    k_init <<<1, 256, 0, stream>>>(gcur, cap, offsets, W1, Wl, N, E);
    k_fat  <<<gemmB + nchunk, 256, 0, stream>>>(x, Wl, h1, row, col, gcur, binned, E, N, nchunk);
    k_csr2 <<<2 * K_used, 512, 0, stream>>>(binned, gcur, cap, offsets, dinv, srcs, h1, N);
    k_agg1 <<<(int)DIV_UP((long long)N * 32, 256), 256, 0, stream>>>(offsets, srcs, dinv, h1, b1, W2, tw, N);
    k_agg2 <<<(int)DIV_UP((long long)N * 16, 256), 256, 0, stream>>>(offsets, srcs, dinv, tw, b2, (float*)d_out, N);
}

// Round 10
// 271.772 us; speedup vs baseline: 1.0984x; 1.0318x over previous
//
#include <hip/hip_runtime.h>
#include <hip/hip_fp16.h>
#include <math.h>

#define DIV_UP(a,b) (((a)+(b)-1)/(b))

typedef _Float16 f16x8 __attribute__((ext_vector_type(8)));
typedef float    f32x4 __attribute__((ext_vector_type(4)));

// ======================= single-pass padded bin sort =======================
// SHIFT=9: bins of 512 targets; bin = col>>9 (K_used = ceil(N/512) <= 256).
// Entry packed as (src << 9) | (col & 511) — src<2^17, fits 26 bits.
#define SHIFT 9
#define TPB   (1 << SHIFT)          /* targets per bin = 512 */
#define LMASK (TPB - 1)
#define CHUNK 4096                  /* edges per binning block */

// --- init: per-bin cursors, CSR sentinel, and W1 -> f16 B-frag layout (16KB). ---
__global__ __launch_bounds__(256) void k_init(int* __restrict__ gcur, int cap,
                                              int* __restrict__ offsets,
                                              const float* __restrict__ W,
                                              _Float16* __restrict__ Wl, int N, int E) {
    const int t = threadIdx.x;
    gcur[t] = t * cap;
    if (t == 0) offsets[N] = E;
#pragma unroll
    for (int c = 0; c < 4; ++c) {
        int chunk = t + 256 * c;            // 0..1023
        int m0 = chunk & 15;
        int q  = (chunk >> 4) & 3;
        int ct = (chunk >> 6) & 1;
        int kc = chunk >> 7;
        int n  = ct * 16 + m0;
        f16x8 v;
#pragma unroll
        for (int j = 0; j < 8; ++j)
            v[j] = (_Float16)W[(kc * 32 + q * 8 + j) * 32 + n];
        *(f16x8*)&Wl[(size_t)chunk * 8] = v;   // 16B coalesced store
    }
}

// ================== FAT kernel: gemm1 + binA, interleaved block roles ==================
// (round-5 verbatim — champion 274.5us config)
__global__ __launch_bounds__(256) void k_fat(const float* __restrict__ x,
                                             const _Float16* __restrict__ Wl,
                                             __half* __restrict__ h1,
                                             const int* __restrict__ row,
                                             const int* __restrict__ col,
                                             int* __restrict__ gcur,
                                             unsigned* __restrict__ binned,
                                             int E, int N, int nchunk) {
    __shared__ __align__(16) char smem[24608];   // union: gemm WlT 16KB | binA 24KB + wtot
    const int t = threadIdx.x;
    const int bid = blockIdx.x;
    const bool isBin = (bid < 2 * nchunk) && (bid & 1);

    if (!isBin) {
        // ------------------- GEMM branch -------------------
        const int gb = (bid < 2 * nchunk) ? (bid >> 1) : (bid - nchunk);
        _Float16* WlT = (_Float16*)smem;

        const uint4* Wg4 = (const uint4*)Wl;
#pragma unroll
        for (int i = 0; i < 4; ++i)
            ((uint4*)WlT)[t + 256 * i] = Wg4[t + 256 * i];
        __syncthreads();

        const int lane = t & 63;
        const int wv   = t >> 6;        // wave 0..3
        const int m    = lane & 15;
        const int q    = lane >> 4;     // 0..3

        const int rowA   = gb * 64 + wv * 16 + m;
        const int rclamp = min(rowA, N - 1);
        const float* xr  = x + (long long)rclamp * 256 + q * 8;

        float4 va[16];
#pragma unroll
        for (int kc = 0; kc < 8; ++kc) {
            va[2 * kc]     = *(const float4*)(xr + kc * 32);
            va[2 * kc + 1] = *(const float4*)(xr + kc * 32 + 4);
        }
        __builtin_amdgcn_sched_barrier(0);

        f32x4 c0 = {0.f, 0.f, 0.f, 0.f}, c1 = {0.f, 0.f, 0.f, 0.f};
#pragma unroll
        for (int kc = 0; kc < 8; ++kc) {
            f16x8 b0 = *(const f16x8*)&WlT[(size_t)((kc * 2 + 0) * 64 + lane) * 8];
            f16x8 b1 = *(const f16x8*)&WlT[(size_t)((kc * 2 + 1) * 64 + lane) * 8];
            float4 v0 = va[2 * kc], v1 = va[2 * kc + 1];
            f16x8 a;
            a[0] = (_Float16)v0.x; a[1] = (_Float16)v0.y;
            a[2] = (_Float16)v0.z; a[3] = (_Float16)v0.w;
            a[4] = (_Float16)v1.x; a[5] = (_Float16)v1.y;
            a[6] = (_Float16)v1.z; a[7] = (_Float16)v1.w;
            c0 = __builtin_amdgcn_mfma_f32_16x16x32_f16(a, b0, c0, 0, 0, 0);
            c1 = __builtin_amdgcn_mfma_f32_16x16x32_f16(a, b1, c1, 0, 0, 0);
        }

        const int orow = gb * 64 + wv * 16 + q * 4;
#pragma unroll
        for (int r = 0; r < 4; ++r) {
            int gr = orow + r;
            if (gr < N) {
                h1[gr * 32 + m]      = __float2half(c0[r]);
                h1[gr * 32 + 16 + m] = __float2half(c1[r]);
            }
        }
    } else {
        // ------------------- binA branch -------------------
        int* hist  = (int*)smem;
        int* loff  = hist + 256;
        int* gbase = loff + 256;
        int* lcur  = gbase + 256;
        unsigned* staged     = (unsigned*)(smem + 4096);
        unsigned char* binOf = (unsigned char*)(smem + 4096 + 16384);
        int* wtot            = (int*)(smem + 4096 + 16384 + 4096);

        const int base = (bid >> 1) * CHUNK;
        const int n = min(CHUNK, E - base);

        hist[t] = 0;
        __syncthreads();

        unsigned pk[CHUNK / 256];
        int bn[CHUNK / 256];
#pragma unroll
        for (int k = 0; k < CHUNK / 256; ++k) {
            int i = base + t + k * 256;
            if (i < E) {
                int c = col[i], r = row[i];
                bn[k] = c >> SHIFT;
                pk[k] = ((unsigned)r << SHIFT) | (unsigned)(c & LMASK);
                atomicAdd(&hist[bn[k]], 1);
            } else bn[k] = -1;
        }
        __syncthreads();

        const int hv = hist[t];
        int sc = hv;
#pragma unroll
        for (int s = 1; s < 64; s <<= 1) {
            int y = __shfl_up(sc, s, 64);
            if ((t & 63) >= s) sc += y;
        }
        if ((t & 63) == 63) wtot[t >> 6] = sc;
        __syncthreads();
        int woff = 0;
#pragma unroll
        for (int j = 0; j < 3; ++j) if (j < (t >> 6)) woff += wtot[j];
        const int excl = sc + woff - hv;
        gbase[t] = hv ? atomicAdd(&gcur[t], hv) : 0;   // reserve space in bin region
        lcur[t] = excl;
        loff[t] = excl;
        __syncthreads();

#pragma unroll
        for (int k = 0; k < CHUNK / 256; ++k) {
            if (bn[k] >= 0) {
                int p = atomicAdd(&lcur[bn[k]], 1);
                staged[p] = pk[k];
                binOf[p] = (unsigned char)bn[k];
            }
        }
        __syncthreads();

        for (int i = t; i < n; i += 256) {
            int bb = binOf[i];
            binned[gbase[bb] + (i - loff[bb])] = staged[i];
        }
    }
}

// --- fused CSR build + h1 scaling, 1024 threads/block (round-5 verbatim) ---
__global__ __launch_bounds__(1024) void k_csr2(const unsigned* __restrict__ binned,
                                               const int* __restrict__ gcur, int cap,
                                               int* __restrict__ offsets,
                                               float* __restrict__ dinv,
                                               int* __restrict__ srcs,
                                               __half* __restrict__ h1, int N) {
    __shared__ int h[TPB];
    __shared__ int cur[TPB];
    __shared__ float sdi[TPB];
    __shared__ int wred[16];
    const int t = threadIdx.x, b = blockIdx.x;
    const int lane = t & 63, wv = t >> 6;      // 16 waves
    const int beg = b * cap, end = gcur[b];

    // obase = sum_{i<b} (gcur[i]-i*cap) via wave butterfly (contributions only t<256)
    int contrib = (t < 256 && t < b) ? (gcur[t] - t * cap) : 0;
#pragma unroll
    for (int s = 1; s < 64; s <<= 1) contrib += __shfl_xor(contrib, s, 64);
    if (t < TPB) h[t] = 0;
    if (lane == 0 && wv < 4) wred[wv] = contrib;
    __syncthreads();
    const int obase = wred[0] + wred[1] + wred[2] + wred[3];

    for (int i = beg + t; i < end; i += 1024)
        atomicAdd(&h[binned[i] & LMASK], 1);
    __syncthreads();

    // exclusive scan of h[512] via 8 wave-scans + cross-wave fixup
    const int cnt = (t < TPB) ? h[t] : 0;
    int sc = cnt;
#pragma unroll
    for (int s = 1; s < 64; s <<= 1) {
        int y = __shfl_up(sc, s, 64);
        if (lane >= s) sc += y;
    }
    if (t < TPB && lane == 63) wred[8 + wv] = sc;   // wv 0..7
    __syncthreads();
    if (t < TPB) {
        int woff = 0;
        for (int j = 0; j < wv; ++j) woff += wred[8 + j];
        const int excl = sc + woff - cnt;
        const int g = (b << SHIFT) + t;
        const int pos0 = obase + excl;
        float di = 0.f;
        if (g < N) {
            offsets[g] = pos0;
            di = rsqrtf((float)(1 + cnt));   // +1 self-loop
            dinv[g] = di;
        }
        cur[t] = pos0;
        sdi[t] = di;
    }
    __syncthreads();

    for (int i = beg + t; i < end; i += 1024) {
        unsigned v = binned[i];
        int pos = atomicAdd(&cur[v & LMASK], 1);
        srcs[pos] = (int)(v >> SHIFT);
    }

    // scale this bin's h1 rows: h1w = dinv * h1 (32B per thread, 2 threads/row)
    const int node = (b << SHIFT) + (t >> 1);
    if (node < N) {
        float di = sdi[t >> 1];
        uint4* hp4 = (uint4*)(h1 + (size_t)node * 32) + (t & 1) * 2;
#pragma unroll
        for (int k4 = 0; k4 < 2; ++k4) {
            uint4 v = hp4[k4];
            __half2* ph = (__half2*)&v;
#pragma unroll
            for (int k2 = 0; k2 < 4; ++k2) {
                float2 u = __half22float2(ph[k2]);
                ph[k2] = __floats2half2_rn(u.x * di, u.y * di);
            }
            hp4[k4] = v;
        }
    }
}

// ====== agg1: Σ h1w[src]; fuse relu+b1+W2 GEMV; write tw = dinv*t (half2) ======
// half-wave per node; lane = (sub=edge-slot 0..7, q=feature-octet 0..3).
// Gather loop unrolled x4 (32 edges in flight: 8 VMEM/lane) — avg deg 32 means one
// iteration covers a whole node; was 2 serial dependent trips at x2 unroll.
__global__ void k_agg1(const int* __restrict__ offsets, const int* __restrict__ srcs,
                       const float* __restrict__ dinv, const __half* __restrict__ h1w,
                       const float* __restrict__ b1, const float* __restrict__ W2,
                       __half2* __restrict__ tw, int N) {
    long long g = (long long)blockIdx.x * blockDim.x + threadIdx.x;
    int node = (int)(g >> 5), f = (int)(g & 31);
    if (node >= N) return;
    const int sub = f >> 2, q = f & 3;
    const int beg = offsets[node], end = offsets[node + 1];
    const uint4* h4 = (const uint4*)h1w;   // 4 uint4 per 32-feat row

    float a0 = 0.f, a1 = 0.f, a2 = 0.f, a3 = 0.f;
    float a4 = 0.f, a5 = 0.f, a6 = 0.f, a7 = 0.f;

    for (int j = beg; j < end; j += 32) {
        int e0 = j + sub, e1 = j + 8 + sub, e2 = j + 16 + sub, e3 = j + 24 + sub;
        int s0 = srcs[min(e0, end - 1)];
        int s1 = srcs[min(e1, end - 1)];
        int s2 = srcs[min(e2, end - 1)];
        int s3 = srcs[min(e3, end - 1)];
        float m0 = (e0 < end) ? 1.f : 0.f;
        float m1 = (e1 < end) ? 1.f : 0.f;
        float m2 = (e2 < end) ? 1.f : 0.f;
        float m3 = (e3 < end) ? 1.f : 0.f;
        uint4 rv0 = h4[s0 * 4 + q];
        uint4 rv1 = h4[s1 * 4 + q];
        uint4 rv2 = h4[s2 * 4 + q];
        uint4 rv3 = h4[s3 * 4 + q];
        __half2 p; float2 u;
#define ACCQ(RV, M)                                                                     \
        p = *(__half2*)&RV.x; u = __half22float2(p); a0 = fmaf(u.x, M, a0); a1 = fmaf(u.y, M, a1); \
        p = *(__half2*)&RV.y; u = __half22float2(p); a2 = fmaf(u.x, M, a2); a3 = fmaf(u.y, M, a3); \
        p = *(__half2*)&RV.z; u = __half22float2(p); a4 = fmaf(u.x, M, a4); a5 = fmaf(u.y, M, a5); \
        p = *(__half2*)&RV.w; u = __half22float2(p); a6 = fmaf(u.x, M, a6); a7 = fmaf(u.y, M, a7);
        ACCQ(rv0, m0)
        ACCQ(rv1, m1)
        ACCQ(rv2, m2)
        ACCQ(rv3, m3)
#undef ACCQ
    }
#pragma unroll
    for (int s = 4; s < 32; s <<= 1) {
        a0 += __shfl_xor(a0, s, 32); a1 += __shfl_xor(a1, s, 32);
        a2 += __shfl_xor(a2, s, 32); a3 += __shfl_xor(a3, s, 32);
        a4 += __shfl_xor(a4, s, 32); a5 += __shfl_xor(a5, s, 32);
        a6 += __shfl_xor(a6, s, 32); a7 += __shfl_xor(a7, s, 32);
    }
    if (sub == 0) {   // lanes 0..3 hold full sums for feature octets q=0..3
        float di = dinv[node];
        uint4 rv = h4[node * 4 + q];   // self-loop row (already dinv-scaled)
        float sf[8];
        {
            __half2 p; float2 u;
            p = *(__half2*)&rv.x; u = __half22float2(p); sf[0] = u.x; sf[1] = u.y;
            p = *(__half2*)&rv.y; u = __half22float2(p); sf[2] = u.x; sf[3] = u.y;
            p = *(__half2*)&rv.z; u = __half22float2(p); sf[4] = u.x; sf[5] = u.y;
            p = *(__half2*)&rv.w; u = __half22float2(p); sf[6] = u.x; sf[7] = u.y;
        }
        float av[8] = {a0, a1, a2, a3, a4, a5, a6, a7};
        float t0 = 0.f, t1 = 0.f;
#pragma unroll
        for (int k = 0; k < 8; ++k) {
            int feat = q * 8 + k;
            float hv = fmaf(di, av[k] + sf[k], b1[feat]);
            hv = fmaxf(hv, 0.f);
            t0 = fmaf(hv, W2[feat * 2 + 0], t0);
            t1 = fmaf(hv, W2[feat * 2 + 1], t1);
        }
        t0 += __shfl_xor(t0, 1, 32); t0 += __shfl_xor(t0, 2, 32);
        t1 += __shfl_xor(t1, 1, 32); t1 += __shfl_xor(t1, 2, 32);
        if (q == 0) tw[node] = __floats2half2_rn(di * t0, di * t1);
    }
}

// ====== agg2: Σ tw[src] (half2, 4B/edge); 16 lanes/node; unrolled x2 ======
__global__ void k_agg2(const int* __restrict__ offsets, const int* __restrict__ srcs,
                       const float* __restrict__ dinv, const __half2* __restrict__ tw,
                       const float* __restrict__ b2, float* __restrict__ out, int N) {
    long long g = (long long)blockIdx.x * blockDim.x + threadIdx.x;
    int node = (int)(g >> 4), f = (int)(g & 15);
    if (node >= N) return;
    int beg = offsets[node], end = offsets[node + 1];
    float a0 = 0.f, a1 = 0.f;
    for (int j = beg + f; j < end; j += 32) {
        int e1 = j + 16;
        int s0 = srcs[j];
        int s1 = srcs[min(e1, end - 1)];
        float m1 = (e1 < end) ? 1.f : 0.f;
        float2 u0 = __half22float2(tw[s0]);
        float2 u1 = __half22float2(tw[s1]);
        a0 += u0.x + m1 * u1.x;
        a1 += u0.y + m1 * u1.y;
    }
#pragma unroll
    for (int s = 8; s; s >>= 1) {   // masks <16 stay within the 16-lane group
        a0 += __shfl_xor(a0, s, 64);
        a1 += __shfl_xor(a1, s, 64);
    }
    if (f == 0) {
        float di = dinv[node];
        float2 u = __half22float2(tw[node]);
        float z0 = di * (a0 + u.x) + b2[0];
        float z1 = di * (a1 + u.y) + b2[1];
        float m = fmaxf(z0, z1);
        float lse = m + logf(expf(z0 - m) + expf(z1 - m));
        ((float2*)out)[node] = float2{z0 - lse, z1 - lse};
    }
}

extern "C" void kernel_launch(void* const* d_in, const int* in_sizes, int n_in,
                              void* d_out, int out_size, void* d_ws, size_t ws_size,
                              hipStream_t stream) {
    const float* x  = (const float*)d_in[0];
    const int*   ei = (const int*)d_in[1];
    const float* W1 = (const float*)d_in[2];
    const float* b1 = (const float*)d_in[3];
    const float* W2 = (const float*)d_in[4];
    const float* b2 = (const float*)d_in[5];

    const int H = in_sizes[3];           // 32
    const int D = in_sizes[2] / H;       // 256
    const int N = in_sizes[0] / D;       // 100000
    const int E = in_sizes[1] / 2;       // 3200000
    (void)H; (void)n_in; (void)out_size; (void)ws_size;

    const int* row = ei;                 // sources
    const int* col = ei + E;             // targets

    const int K_used = ((N - 1) >> SHIFT) + 1;        // 196 bins
    const int cap    = (DIV_UP(E, K_used) * 5 / 4 + 255) & ~255;  // +25% margin
    const int nchunk = DIV_UP(E, CHUNK);              // 782 binning blocks
    const int gemmB  = DIV_UP(N, 64);                 // 1563 gemm blocks

    char* p = (char*)d_ws;
    auto alloc = [&](size_t bytes) { char* q = p; p += (bytes + 255) & ~(size_t)255; return q; };
    int*      offsets = (int*)     alloc((size_t)(N + 1) * 4);
    int*      gcur    = (int*)     alloc(256 * 4);
    _Float16* Wl      = (_Float16*)alloc(8192 * 2);
    float*    dinv    = (float*)   alloc((size_t)N * 4);
    unsigned* binned  = (unsigned*)alloc((size_t)K_used * cap * 4);
    __half*   h1      = (__half*)  alloc((size_t)N * 32 * 2);
    int*      srcs    = (int*)     alloc((size_t)E * 4);
    __half2*  tw      = (__half2*) alloc((size_t)N * 4);

    k_init <<<1, 256, 0, stream>>>(gcur, cap, offsets, W1, Wl, N, E);
    k_fat  <<<gemmB + nchunk, 256, 0, stream>>>(x, Wl, h1, row, col, gcur, binned, E, N, nchunk);
    k_csr2 <<<K_used, 1024, 0, stream>>>(binned, gcur, cap, offsets, dinv, srcs, h1, N);
    k_agg1 <<<(int)DIV_UP((long long)N * 32, 256), 256, 0, stream>>>(offsets, srcs, dinv, h1, b1, W2, tw, N);
    k_agg2 <<<(int)DIV_UP((long long)N * 16, 256), 256, 0, stream>>>(offsets, srcs, dinv, tw, b2, (float*)d_out, N);
}